// Round 11
// baseline (165865.283 us; speedup 1.0000x reference)
//
#include <hip/hip_runtime.h>
#include <stdint.h>

#define VOCAB 60
#define EMB   100
#define HID   100
#define SEQN  262144
#define NPROJ 300     // 3*HID
#define KPAD  128     // K padded to 4 MFMA K-steps of 32
#define MPAD  320     // rows padded to 4 waves * 5 tiles * 16
#define NMFW  4       // MFMA waves (= all waves)
#define MT    5       // M-tiles per wave
#define KS    4       // K-steps

typedef float    f32x4 __attribute__((ext_vector_type(4)));
typedef _Float16 h16x8 __attribute__((ext_vector_type(8)));

__device__ __forceinline__ float fast_sig(float x) {
    return __builtin_amdgcn_rcpf(1.0f + __builtin_amdgcn_exp2f(-1.442695041f * x));
}
__device__ __forceinline__ float fast_tanh(float x) {
    return 2.0f * __builtin_amdgcn_rcpf(1.0f + __builtin_amdgcn_exp2f(-2.885390082f * x)) - 1.0f;
}

// Job 1: proj[v][j] = emb[v]·w_ih[j] + b_ih[j] + (j<200 ? b_hh[j] : 0)  (fp32)
// Job 2: afrag = W_hh in MFMA A-fragment order (f16, zero-padded)  [r10-verified]
__global__ void precompute_kernel(const float* __restrict__ emb,
                                  const float* __restrict__ w_ih,
                                  const float* __restrict__ b_ih,
                                  const float* __restrict__ b_hh,
                                  const float* __restrict__ w_hh,
                                  float* __restrict__ proj,
                                  _Float16* __restrict__ afrag)
{
    int idx = blockIdx.x * blockDim.x + threadIdx.x;
    if (idx < VOCAB * NPROJ) {
        int v = idx / NPROJ, j = idx - v * NPROJ;
        float acc = b_ih[j] + (j < 2 * HID ? b_hh[j] : 0.0f);
        const float* er = emb  + v * EMB;
        const float* wr = w_ih + j * EMB;
        #pragma unroll 4
        for (int k = 0; k < EMB; ++k) acc = fmaf(er[k], wr[k], acc);
        proj[idx] = acc;
    }
    if (idx < NMFW * MT * KS * 64 * 8) {     // 40960 halves
        int e    = idx & 7;
        int lane = (idx >> 3) & 63;
        int q    = idx >> 9;
        int ks   = q & 3;
        int q2   = q >> 2;
        int m    = q2 % MT;
        int w    = q2 / MT;
        int row  = w * 80 + m * 16 + (lane & 15);
        int k    = ks * 32 + ((lane >> 4) << 3) + e;
        afrag[idx] = (row < NPROJ && k < HID)
                   ? (_Float16)w_hh[row * HID + k] : (_Float16)0.0f;
    }
}

#define MFMA(A, B, C) __builtin_amdgcn_mfma_f32_16x16x32_f16((A), (B), (C), 0, 0, 0)

#define LOADF(M, K) \
    h16x8 af_##M##_##K = *(const h16x8*)(afrag + ((((wave*MT+(M))*KS+(K))*64) + lane) * 8);

// 256 threads = 4 waves (1/SIMD). Every wave: MFMA quarter of u = W_hh·h
// (weights AGPR-parked, consumed in place), then — after ONE barrier —
// redundantly computes ALL 100 gates and writes its own private h copy
// (next step's B-read is own-wave LDS, ordered by lgkmcnt -> no 2nd barrier).
// Shared u_lds is double-buffered to kill the WAR race across the barrier.
__global__ __launch_bounds__(256, 1) __attribute__((amdgpu_waves_per_eu(1, 1)))
void gru_seq_kernel(const int*      __restrict__ x,
                    const float*    __restrict__ b_hh,
                    const float*    __restrict__ proj,
                    const _Float16* __restrict__ afrag,
                    float*          __restrict__ out)
{
    __shared__ __align__(16) _Float16 h_priv[NMFW][KPAD];  // per-wave h (f16)
    __shared__ __align__(16) float    u_lds[2][MPAD];      // double-buffered u

    const int tid  = threadIdx.x;
    const int wave = tid >> 6;
    const int lane = tid & 63;

    const int  j0   = lane;                       // gate index 0 (0..63)
    const bool has1 = (lane < HID - 64);          // lanes 0..35
    const int  j1   = has1 ? (lane + 64) : (HID - 1);

    h_priv[wave][lane]      = (_Float16)0.0f;
    h_priv[wave][lane + 64] = (_Float16)0.0f;

    // 20 A fragments per wave (80 AGPR dwords), AGPR-parked.
    LOADF(0,0) LOADF(0,1) LOADF(0,2) LOADF(0,3)
    LOADF(1,0) LOADF(1,1) LOADF(1,2) LOADF(1,3)
    LOADF(2,0) LOADF(2,1) LOADF(2,2) LOADF(2,3)
    LOADF(3,0) LOADF(3,1) LOADF(3,2) LOADF(3,3)
    LOADF(4,0) LOADF(4,1) LOADF(4,2) LOADF(4,3)

    const float bhn0 = b_hh[2 * HID + j0];
    const float bhn1 = b_hh[2 * HID + j1];
    float hold0 = 0.0f, hold1 = 0.0f;

    // Software-pipelined token/proj lookups (1 step of slack, L2-resident).
    int tok = x[0];
    float xr0 = proj[tok * NPROJ + j0];
    float xz0 = proj[tok * NPROJ + HID + j0];
    float xn0 = proj[tok * NPROJ + 2 * HID + j0];
    float xr1 = proj[tok * NPROJ + j1];
    float xz1 = proj[tok * NPROJ + HID + j1];
    float xn1 = proj[tok * NPROJ + 2 * HID + j1];
    int tok_next = x[1];

    __syncthreads();

    for (int t = 0; t < SEQN; ++t) {
        const int cur = t & 1;

        // Pin fragments in AGPRs (loop-carried; MFMA reads them in place).
        asm("" : "+a"(af_0_0), "+a"(af_0_1), "+a"(af_0_2), "+a"(af_0_3), "+a"(af_1_0));
        asm("" : "+a"(af_1_1), "+a"(af_1_2), "+a"(af_1_3), "+a"(af_2_0), "+a"(af_2_1));
        asm("" : "+a"(af_2_2), "+a"(af_2_3), "+a"(af_3_0), "+a"(af_3_1), "+a"(af_3_2));
        asm("" : "+a"(af_3_3), "+a"(af_4_0), "+a"(af_4_1), "+a"(af_4_2), "+a"(af_4_3));

        // Prefetch step t+1 inputs (overlaps the MFMA phase).
        int   tok_nn = x[(t + 2 < SEQN) ? (t + 2) : (SEQN - 1)];
        float xr0n = proj[tok_next * NPROJ + j0];
        float xz0n = proj[tok_next * NPROJ + HID + j0];
        float xn0n = proj[tok_next * NPROJ + 2 * HID + j0];
        float xr1n = proj[tok_next * NPROJ + j1];
        float xz1n = proj[tok_next * NPROJ + HID + j1];
        float xn1n = proj[tok_next * NPROJ + 2 * HID + j1];

        // ---- MFMA phase: B-prep (4 broadcast b128 of own h) + 20 MFMA ----
        const _Float16* hp = h_priv[wave];
        const int ko = (lane >> 4) << 3;
        h16x8 b0 = *(const h16x8*)(hp +  0 + ko);
        h16x8 b1 = *(const h16x8*)(hp + 32 + ko);
        h16x8 b2 = *(const h16x8*)(hp + 64 + ko);
        h16x8 b3 = *(const h16x8*)(hp + 96 + ko);

        // Two accumulators per tile (K-steps 0,1 | 2,3) halve the dep chain.
        f32x4 zz = {0.f, 0.f, 0.f, 0.f};
        f32x4 aA0 = zz, aA1 = zz, aA2 = zz, aA3 = zz, aA4 = zz;
        f32x4 aB0 = zz, aB1 = zz, aB2 = zz, aB3 = zz, aB4 = zz;
        aA0 = MFMA(af_0_0, b0, aA0); aB0 = MFMA(af_0_2, b2, aB0);
        aA1 = MFMA(af_1_0, b0, aA1); aB1 = MFMA(af_1_2, b2, aB1);
        aA2 = MFMA(af_2_0, b0, aA2); aB2 = MFMA(af_2_2, b2, aB2);
        aA3 = MFMA(af_3_0, b0, aA3); aB3 = MFMA(af_3_2, b2, aB3);
        aA4 = MFMA(af_4_0, b0, aA4); aB4 = MFMA(af_4_2, b2, aB4);
        aA0 = MFMA(af_0_1, b1, aA0); aB0 = MFMA(af_0_3, b3, aB0);
        aA1 = MFMA(af_1_1, b1, aA1); aB1 = MFMA(af_1_3, b3, aB1);
        aA2 = MFMA(af_2_1, b1, aA2); aB2 = MFMA(af_2_3, b3, aB2);
        aA3 = MFMA(af_3_1, b1, aA3); aB3 = MFMA(af_3_3, b3, aB3);
        aA4 = MFMA(af_4_1, b1, aA4); aB4 = MFMA(af_4_3, b3, aB4);

        if ((lane & 15) == 0) {
            const int rb = wave * 80 + ((lane >> 4) << 2);
            *(f32x4*)&u_lds[cur][rb +  0] = aA0 + aB0;
            *(f32x4*)&u_lds[cur][rb + 16] = aA1 + aB1;
            *(f32x4*)&u_lds[cur][rb + 32] = aA2 + aB2;
            *(f32x4*)&u_lds[cur][rb + 48] = aA3 + aB3;
            *(f32x4*)&u_lds[cur][rb + 64] = aA4 + aB4;
        }
        __syncthreads();                 // the ONLY barrier per step

        // ---- Gate phase (redundant in every wave): j0 and j1 interleaved ----
        const float* ub = u_lds[cur];
        float uR0 = ub[j0]           + xr0;
        float uZ0 = ub[HID + j0]     + xz0;
        float uN0 = ub[2 * HID + j0] + bhn0;
        float uR1 = ub[j1]           + xr1;
        float uZ1 = ub[HID + j1]     + xz1;
        float uN1 = ub[2 * HID + j1] + bhn1;

        float r0 = fast_sig(uR0), r1 = fast_sig(uR1);
        float z0 = fast_sig(uZ0), z1 = fast_sig(uZ1);
        float n0 = fast_tanh(xn0 + r0 * uN0);
        float n1 = fast_tanh(xn1 + r1 * uN1);
        float hn0 = n0 + z0 * (hold0 - n0);
        float hn1 = n1 + z1 * (hold1 - n1);
        hold0 = hn0;  hold1 = hn1;

        h_priv[wave][j0] = (_Float16)hn0;           // own copy: no barrier
        if (has1) h_priv[wave][j1] = (_Float16)hn1;

        tok_next = tok_nn;
        xr0 = xr0n;  xz0 = xz0n;  xn0 = xn0n;
        xr1 = xr1n;  xz1 = xz1n;  xn1 = xn1n;
    }

    if (wave == 0) {
        out[j0] = hold0;
        if (has1) out[j1] = hold1;
    }
}

extern "C" void kernel_launch(void* const* d_in, const int* in_sizes, int n_in,
                              void* d_out, int out_size, void* d_ws, size_t ws_size,
                              hipStream_t stream)
{
    const int*   x    = (const int*)  d_in[0];
    const float* emb  = (const float*)d_in[1];
    const float* w_ih = (const float*)d_in[2];
    const float* w_hh = (const float*)d_in[3];
    const float* b_ih = (const float*)d_in[4];
    const float* b_hh = (const float*)d_in[5];
    float* out = (float*)d_out;

    float*    proj  = (float*)d_ws;                        // 18000 f32 = 72 KB
    _Float16* afrag = (_Float16*)(proj + VOCAB * NPROJ);   // 40960 f16 = 80 KB

    const int total = NMFW * MT * KS * 64 * 8;             // 40960 covers both jobs
    precompute_kernel<<<(total + 255) / 256, 256, 0, stream>>>(
        emb, w_ih, b_ih, b_hh, w_hh, proj, afrag);
    gru_seq_kernel<<<1, 256, 0, stream>>>(x, b_hh, proj, afrag, out);
}

// Round 12
// 121895.898 us; speedup vs baseline: 1.3607x; 1.3607x over previous
//
#include <hip/hip_runtime.h>
#include <stdint.h>

#define VOCAB 60
#define EMB   100
#define HID   100
#define SEQN  262144
#define NPROJ 300     // 3*HID
#define KPAD  128     // K padded to 4 MFMA K-steps of 32
#define NMFW  4       // waves
#define MT    6       // M-tiles per wave (96 rows; triple-grouped)
#define KS    4       // K-steps

typedef float    f32x4 __attribute__((ext_vector_type(4)));
typedef _Float16 h16x8 __attribute__((ext_vector_type(8)));

__device__ __forceinline__ float fast_sig(float x) {
    return __builtin_amdgcn_rcpf(1.0f + __builtin_amdgcn_exp2f(-1.442695041f * x));
}
__device__ __forceinline__ float fast_tanh(float x) {
    return 2.0f * __builtin_amdgcn_rcpf(1.0f + __builtin_amdgcn_exp2f(-2.885390082f * x)) - 1.0f;
}

// Job 1: proj[v][j] = emb[v]·w_ih[j] + b_ih[j] + (j<200 ? b_hh[j] : 0)  (fp32)
// Job 2: afrag = W_hh in TRIPLE-GROUPED MFMA A-fragment order (f16, padded):
//   wave w, tile m, A-row rho=lane&15 (G=rho>>2, q=rho&3):
//     wh = m%3 (0=r,1=z,2=n), j = 32w + 8G + 2q + (m>=3), W-row = wh*100+j
//   k = ks*32 + (lane>>4)*8 + e
__global__ void precompute_kernel(const float* __restrict__ emb,
                                  const float* __restrict__ w_ih,
                                  const float* __restrict__ b_ih,
                                  const float* __restrict__ b_hh,
                                  const float* __restrict__ w_hh,
                                  float* __restrict__ proj,
                                  _Float16* __restrict__ afrag)
{
    int idx = blockIdx.x * blockDim.x + threadIdx.x;
    if (idx < VOCAB * NPROJ) {
        int v = idx / NPROJ, j = idx - v * NPROJ;
        float acc = b_ih[j] + (j < 2 * HID ? b_hh[j] : 0.0f);
        const float* er = emb  + v * EMB;
        const float* wr = w_ih + j * EMB;
        #pragma unroll 4
        for (int k = 0; k < EMB; ++k) acc = fmaf(er[k], wr[k], acc);
        proj[idx] = acc;
    }
    if (idx < NMFW * MT * KS * 64 * 8) {      // 49152 halves
        int e    = idx & 7;
        int lane = (idx >> 3) & 63;
        int q0   = idx >> 9;
        int ks   = q0 & 3;
        int q1   = q0 >> 2;
        int m    = q1 % MT;
        int w    = q1 / MT;
        int rho  = lane & 15;
        int G    = rho >> 2, q = rho & 3;
        int wh   = m % 3;
        int j    = 32 * w + 8 * G + 2 * q + (m >= 3 ? 1 : 0);
        int k    = ks * 32 + ((lane >> 4) << 3) + e;
        afrag[idx] = (j < HID && k < HID)
                   ? (_Float16)w_hh[(wh * HID + j) * HID + k] : (_Float16)0.0f;
    }
}

#define MFMA(A, B, C) __builtin_amdgcn_mfma_f32_16x16x32_f16((A), (B), (C), 0, 0, 0)

#define LOADF(M, K) \
    h16x8 af_##M##_##K = *(const h16x8*)(afrag + ((((wave*MT+(M))*KS+(K))*64) + lane) * 8);

// Cheap barrier: drain LDS only; leave global prefetch (vmcnt) in flight.
#define BAR() asm volatile("s_waitcnt lgkmcnt(0)\n\ts_barrier" ::: "memory")

// 256 threads = 4 waves (1/SIMD). Each wave: 24 MFMA produce complete
// (r,z,n) u-triples IN REGISTERS (triple-grouped mapping); lane c<8 of each
// 16-lane group muxes out its triple (compile-time-safe cndmask tree),
// runs one gate chain, publishes h_j to double-buffered shared h.
// u NEVER touches LDS. ONE (cheap) barrier per step.
__global__ __launch_bounds__(256, 1) __attribute__((amdgpu_waves_per_eu(1, 1)))
void gru_seq_kernel(const int*      __restrict__ x,
                    const float*    __restrict__ b_hh,
                    const float*    __restrict__ proj,
                    const _Float16* __restrict__ afrag,
                    float*          __restrict__ out)
{
    __shared__ __align__(16) _Float16 hbuf[2][KPAD];   // 512 B total

    const int tid  = threadIdx.x;
    const int wave = tid >> 6;
    const int lane = tid & 63;
    const int G    = lane >> 4;
    const int c    = lane & 15;

    const int  jv     = 32 * wave + 8 * G + c;       // valid when c<8
    const bool active = (c < 8) && (jv < HID);
    const int  j      = active ? jv : 0;
    const int  q2     = (c >> 1) & 3;                // component selector
    const bool hi     = (c & 1);                     // tile-half selector

    if (tid < 2 * KPAD) ((_Float16*)hbuf)[tid] = (_Float16)0.0f;

    // 24 A fragments (96 AGPR dwords), AGPR-parked.
    LOADF(0,0) LOADF(0,1) LOADF(0,2) LOADF(0,3)
    LOADF(1,0) LOADF(1,1) LOADF(1,2) LOADF(1,3)
    LOADF(2,0) LOADF(2,1) LOADF(2,2) LOADF(2,3)
    LOADF(3,0) LOADF(3,1) LOADF(3,2) LOADF(3,3)
    LOADF(4,0) LOADF(4,1) LOADF(4,2) LOADF(4,3)
    LOADF(5,0) LOADF(5,1) LOADF(5,2) LOADF(5,3)

    const float bhn = b_hh[2 * HID + j];
    float hold = 0.0f;

    // Software-pipelined token/proj lookups (1 step of slack, L2-resident).
    int tok = x[0];
    float xr = proj[tok * NPROJ + j];
    float xz = proj[tok * NPROJ + HID + j];
    float xn = proj[tok * NPROJ + 2 * HID + j];
    int tok_next = x[1];

    __syncthreads();

    for (int t = 0; t < SEQN; ++t) {
        const int cur = t & 1;

        // Pin fragments in AGPRs (loop-carried; MFMA consumes them in place).
        asm("" : "+a"(af_0_0), "+a"(af_0_1), "+a"(af_0_2), "+a"(af_0_3), "+a"(af_1_0));
        asm("" : "+a"(af_1_1), "+a"(af_1_2), "+a"(af_1_3), "+a"(af_2_0), "+a"(af_2_1));
        asm("" : "+a"(af_2_2), "+a"(af_2_3), "+a"(af_3_0), "+a"(af_3_1), "+a"(af_3_2));
        asm("" : "+a"(af_3_3), "+a"(af_4_0), "+a"(af_4_1), "+a"(af_4_2), "+a"(af_4_3));
        asm("" : "+a"(af_5_0), "+a"(af_5_1), "+a"(af_5_2), "+a"(af_5_3));

        // Prefetch step t+1 inputs (vmcnt stays in flight across the barrier).
        int   tok_nn = x[(t + 2 < SEQN) ? (t + 2) : (SEQN - 1)];
        float xr_n = proj[tok_next * NPROJ + j];
        float xz_n = proj[tok_next * NPROJ + HID + j];
        float xn_n = proj[tok_next * NPROJ + 2 * HID + j];

        // ---- B-prep: 4 broadcast b128 reads of shared h ----
        const _Float16* hp = hbuf[cur];
        const int ko = (lane >> 4) << 3;
        h16x8 b0 = *(const h16x8*)(hp +  0 + ko);
        h16x8 b1 = *(const h16x8*)(hp + 32 + ko);
        h16x8 b2 = *(const h16x8*)(hp + 64 + ko);
        h16x8 b3 = *(const h16x8*)(hp + 96 + ko);

        // ---- 24 MFMA: 6 independent 4-chains (one per tile) ----
        f32x4 zz = {0.f, 0.f, 0.f, 0.f};
        f32x4 ac0 = zz, ac1 = zz, ac2 = zz, ac3 = zz, ac4 = zz, ac5 = zz;
        ac0 = MFMA(af_0_0, b0, ac0); ac1 = MFMA(af_1_0, b0, ac1);
        ac2 = MFMA(af_2_0, b0, ac2); ac3 = MFMA(af_3_0, b0, ac3);
        ac4 = MFMA(af_4_0, b0, ac4); ac5 = MFMA(af_5_0, b0, ac5);
        ac0 = MFMA(af_0_1, b1, ac0); ac1 = MFMA(af_1_1, b1, ac1);
        ac2 = MFMA(af_2_1, b1, ac2); ac3 = MFMA(af_3_1, b1, ac3);
        ac4 = MFMA(af_4_1, b1, ac4); ac5 = MFMA(af_5_1, b1, ac5);
        ac0 = MFMA(af_0_2, b2, ac0); ac1 = MFMA(af_1_2, b2, ac1);
        ac2 = MFMA(af_2_2, b2, ac2); ac3 = MFMA(af_3_2, b2, ac3);
        ac4 = MFMA(af_4_2, b2, ac4); ac5 = MFMA(af_5_2, b2, ac5);
        ac0 = MFMA(af_0_3, b3, ac0); ac1 = MFMA(af_1_3, b3, ac1);
        ac2 = MFMA(af_2_3, b3, ac2); ac3 = MFMA(af_3_3, b3, ac3);
        ac4 = MFMA(af_4_3, b3, ac4); ac5 = MFMA(af_5_3, b3, ac5);

        // ---- triple mux (compile-time indices only; ~21 cndmask) ----
        f32x4 acR = hi ? ac3 : ac0;
        f32x4 acZ = hi ? ac4 : ac1;
        f32x4 acN = hi ? ac5 : ac2;
        float sRlo = (q2 & 1) ? acR[1] : acR[0], sRhi = (q2 & 1) ? acR[3] : acR[2];
        float sZlo = (q2 & 1) ? acZ[1] : acZ[0], sZhi = (q2 & 1) ? acZ[3] : acZ[2];
        float sNlo = (q2 & 1) ? acN[1] : acN[0], sNhi = (q2 & 1) ? acN[3] : acN[2];
        float sR = (q2 & 2) ? sRhi : sRlo;
        float sZ = (q2 & 2) ? sZhi : sZlo;
        float sN = (q2 & 2) ? sNhi : sNlo;

        // ---- gate chain (one triple per active lane) ----
        float uR = sR + xr;
        float uZ = sZ + xz;
        float uN = sN + bhn;
        float r    = fast_sig(uR);
        float z    = fast_sig(uZ);
        float n    = fast_tanh(xn + r * uN);
        float hnew = n + z * (hold - n);
        hold = hnew;

        if (active) hbuf[cur ^ 1][j] = (_Float16)hnew;
        BAR();                            // lgkmcnt(0) + s_barrier only

        tok = tok_next;  tok_next = tok_nn;
        xr = xr_n;  xz = xz_n;  xn = xn_n;
    }

    if (active) out[j] = hold;
}

extern "C" void kernel_launch(void* const* d_in, const int* in_sizes, int n_in,
                              void* d_out, int out_size, void* d_ws, size_t ws_size,
                              hipStream_t stream)
{
    const int*   x    = (const int*)  d_in[0];
    const float* emb  = (const float*)d_in[1];
    const float* w_ih = (const float*)d_in[2];
    const float* w_hh = (const float*)d_in[3];
    const float* b_ih = (const float*)d_in[4];
    const float* b_hh = (const float*)d_in[5];
    float* out = (float*)d_out;

    float*    proj  = (float*)d_ws;                        // 18000 f32 = 72 KB
    _Float16* afrag = (_Float16*)(proj + VOCAB * NPROJ);   // 49152 f16 = 96 KB

    const int total = NMFW * MT * KS * 64 * 8;             // 49152 covers both jobs
    precompute_kernel<<<(total + 255) / 256, 256, 0, stream>>>(
        emb, w_ih, b_ih, b_hh, w_hh, proj, afrag);
    gru_seq_kernel<<<1, 256, 0, stream>>>(x, b_hh, proj, afrag, out);
}

// Round 13
// 101721.527 us; speedup vs baseline: 1.6306x; 1.1983x over previous
//
#include <hip/hip_runtime.h>
#include <stdint.h>

#define VOCAB 60
#define EMB   100
#define HID   100
#define SEQN  262144
#define NPROJ 300     // 3*HID
#define KPAD  128     // K padded to 4 MFMA K-steps of 32
#define NMFW  4       // waves
#define MT    6       // M-tiles per wave (96 rows; triple-grouped)
#define KS    4       // K-steps

typedef float    f32x4 __attribute__((ext_vector_type(4)));
typedef _Float16 h16x8 __attribute__((ext_vector_type(8)));

__device__ __forceinline__ float fast_sig(float x) {
    return __builtin_amdgcn_rcpf(1.0f + __builtin_amdgcn_exp2f(-1.442695041f * x));
}
__device__ __forceinline__ float fast_tanh(float x) {
    return 2.0f * __builtin_amdgcn_rcpf(1.0f + __builtin_amdgcn_exp2f(-2.885390082f * x)) - 1.0f;
}

// Job 1: proj[v][j] = emb[v]·w_ih[j] + b_ih[j] + (j<200 ? b_hh[j] : 0)  (fp32)
// Job 2: afrag = W_hh in TRIPLE-GROUPED MFMA A-fragment order (f16, padded):
//   wave w, tile m, A-row rho=lane&15 (G=rho>>2, q=rho&3):
//     wh = m%3 (0=r,1=z,2=n), j = 32w + 8G + 2q + (m>=3), W-row = wh*100+j
//   k = ks*32 + (lane>>4)*8 + e                       [r12-verified, absmax ok]
__global__ void precompute_kernel(const float* __restrict__ emb,
                                  const float* __restrict__ w_ih,
                                  const float* __restrict__ b_ih,
                                  const float* __restrict__ b_hh,
                                  const float* __restrict__ w_hh,
                                  float* __restrict__ proj,
                                  _Float16* __restrict__ afrag)
{
    int idx = blockIdx.x * blockDim.x + threadIdx.x;
    if (idx < VOCAB * NPROJ) {
        int v = idx / NPROJ, j = idx - v * NPROJ;
        float acc = b_ih[j] + (j < 2 * HID ? b_hh[j] : 0.0f);
        const float* er = emb  + v * EMB;
        const float* wr = w_ih + j * EMB;
        #pragma unroll 4
        for (int k = 0; k < EMB; ++k) acc = fmaf(er[k], wr[k], acc);
        proj[idx] = acc;
    }
    if (idx < NMFW * MT * KS * 64 * 8) {      // 49152 halves
        int e    = idx & 7;
        int lane = (idx >> 3) & 63;
        int q0   = idx >> 9;
        int ks   = q0 & 3;
        int q1   = q0 >> 2;
        int m    = q1 % MT;
        int w    = q1 / MT;
        int rho  = lane & 15;
        int G    = rho >> 2, q = rho & 3;
        int wh   = m % 3;
        int j    = 32 * w + 8 * G + 2 * q + (m >= 3 ? 1 : 0);
        int k    = ks * 32 + ((lane >> 4) << 3) + e;
        afrag[idx] = (j < HID && k < HID)
                   ? (_Float16)w_hh[(wh * HID + j) * HID + k] : (_Float16)0.0f;
    }
}

#define MFMA(A, B, C) __builtin_amdgcn_mfma_f32_16x16x32_f16((A), (B), (C), 0, 0, 0)

#define LOADF(M, K) \
    h16x8 af_##M##_##K = *(const h16x8*)(afrag + ((((wave*MT+(M))*KS+(K))*64) + lane) * 8);

// Cheap barrier: drain LDS only; leave global prefetch (vmcnt) in flight.
#define BAR() asm volatile("s_waitcnt lgkmcnt(0)\n\ts_barrier" ::: "memory")

// Issue the 4 broadcast b128 reads of h for the NEXT step (pipelined B-prep).
#define B_LOAD(BUF) {                                   \
    const _Float16* hp_ = hbuf[BUF];                    \
    b0 = *(const h16x8*)(hp_ +  0 + ko);                \
    b1 = *(const h16x8*)(hp_ + 32 + ko);                \
    b2 = *(const h16x8*)(hp_ + 64 + ko);                \
    b3 = *(const h16x8*)(hp_ + 96 + ko); }

// One GRU step. CUR/NXT are compile-time buffer indices; TOFF in {0,1}.
// Uses pre-loaded b0..b3 (h of step t); at the end, pre-loads b for step t+1.
#define STEP(CUR, NXT, TOFF) {                                              \
    /* pins: loop-carried AGPR fragments, consumed in place by MFMA */      \
    asm("" : "+a"(af_0_0), "+a"(af_0_1), "+a"(af_0_2), "+a"(af_0_3), "+a"(af_1_0)); \
    asm("" : "+a"(af_1_1), "+a"(af_1_2), "+a"(af_1_3), "+a"(af_2_0), "+a"(af_2_1)); \
    asm("" : "+a"(af_2_2), "+a"(af_2_3), "+a"(af_3_0), "+a"(af_3_1), "+a"(af_3_2)); \
    asm("" : "+a"(af_3_3), "+a"(af_4_0), "+a"(af_4_1), "+a"(af_4_2), "+a"(af_4_3)); \
    asm("" : "+a"(af_5_0), "+a"(af_5_1), "+a"(af_5_2), "+a"(af_5_3));       \
    /* scalar token/prefetch: SALU base + loop-invariant lane offset */     \
    int tt_ = t + (TOFF);                                                   \
    int tok_nn = x[(tt_ + 2 < SEQN) ? (tt_ + 2) : (SEQN - 1)];              \
    int tok_s  = __builtin_amdgcn_readfirstlane(tok_next);                  \
    const float* pb_ = projj + tok_s * NPROJ;                               \
    float xr_n = pb_[0];                                                    \
    float xz_n = pb_[HID];                                                  \
    float xn_n = pb_[2 * HID];                                              \
    /* 24 MFMA: 6 independent 4-chains (b0..b3 pre-loaded last step) */     \
    f32x4 zz = {0.f, 0.f, 0.f, 0.f};                                        \
    f32x4 ac0 = zz, ac1 = zz, ac2 = zz, ac3 = zz, ac4 = zz, ac5 = zz;       \
    ac0 = MFMA(af_0_0, b0, ac0); ac1 = MFMA(af_1_0, b0, ac1);               \
    ac2 = MFMA(af_2_0, b0, ac2); ac3 = MFMA(af_3_0, b0, ac3);               \
    ac4 = MFMA(af_4_0, b0, ac4); ac5 = MFMA(af_5_0, b0, ac5);               \
    ac0 = MFMA(af_0_1, b1, ac0); ac1 = MFMA(af_1_1, b1, ac1);               \
    ac2 = MFMA(af_2_1, b1, ac2); ac3 = MFMA(af_3_1, b1, ac3);               \
    ac4 = MFMA(af_4_1, b1, ac4); ac5 = MFMA(af_5_1, b1, ac5);               \
    ac0 = MFMA(af_0_2, b2, ac0); ac1 = MFMA(af_1_2, b2, ac1);               \
    ac2 = MFMA(af_2_2, b2, ac2); ac3 = MFMA(af_3_2, b2, ac3);               \
    ac4 = MFMA(af_4_2, b2, ac4); ac5 = MFMA(af_5_2, b2, ac5);               \
    ac0 = MFMA(af_0_3, b3, ac0); ac1 = MFMA(af_1_3, b3, ac1);               \
    ac2 = MFMA(af_2_3, b3, ac2); ac3 = MFMA(af_3_3, b3, ac3);               \
    ac4 = MFMA(af_4_3, b3, ac4); ac5 = MFMA(af_5_3, b3, ac5);               \
    /* triple mux (compile-time indices only) */                            \
    f32x4 acR = hi ? ac3 : ac0;                                             \
    f32x4 acZ = hi ? ac4 : ac1;                                             \
    f32x4 acN = hi ? ac5 : ac2;                                             \
    float sRlo = (q2 & 1) ? acR[1] : acR[0], sRhi = (q2 & 1) ? acR[3] : acR[2]; \
    float sZlo = (q2 & 1) ? acZ[1] : acZ[0], sZhi = (q2 & 1) ? acZ[3] : acZ[2]; \
    float sNlo = (q2 & 1) ? acN[1] : acN[0], sNhi = (q2 & 1) ? acN[3] : acN[2]; \
    float sR = (q2 & 2) ? sRhi : sRlo;                                      \
    float sZ = (q2 & 2) ? sZhi : sZlo;                                      \
    float sN = (q2 & 2) ? sNhi : sNlo;                                      \
    /* gate chain */                                                        \
    float r    = fast_sig(sR + xr);                                         \
    float z    = fast_sig(sZ + xz);                                         \
    float n    = fast_tanh(xn + r * (sN + bhn));                            \
    float hnew = n + z * (hold - n);                                        \
    hold = hnew;                                                            \
    if (active) hbuf[NXT][j] = (_Float16)hnew;                              \
    BAR();                                                                  \
    B_LOAD(NXT);            /* pipelined B-prep for the next step */        \
    tok_next = tok_nn;                                                      \
    xr = xr_n;  xz = xz_n;  xn = xn_n; }

// 256 threads = 4 waves (1/SIMD). Each wave: 24 MFMA produce complete (r,z,n)
// u-triples IN REGISTERS; lane c<8 per 16-lane group muxes its triple, runs one
// gate chain, publishes h_j. u never touches LDS; ONE cheap barrier per step;
// B-prep ds_reads pipelined across the iteration boundary; unroll x2.
__global__ __launch_bounds__(256, 1) __attribute__((amdgpu_waves_per_eu(1, 1)))
void gru_seq_kernel(const int*      __restrict__ x,
                    const float*    __restrict__ b_hh,
                    const float*    __restrict__ proj,
                    const _Float16* __restrict__ afrag,
                    float*          __restrict__ out)
{
    __shared__ __align__(16) _Float16 hbuf[2][KPAD];   // 512 B total

    const int tid  = threadIdx.x;
    const int wave = tid >> 6;
    const int lane = tid & 63;
    const int G    = lane >> 4;
    const int c    = lane & 15;
    const int ko   = (lane >> 4) << 3;                 // B k-slice offset

    const int  jv     = 32 * wave + 8 * G + c;         // valid when c<8
    const bool active = (c < 8) && (jv < HID);
    const int  j      = active ? jv : 0;
    const int  q2     = (c >> 1) & 3;                  // component selector
    const bool hi     = (c & 1);                       // tile-half selector

    if (tid < 2 * KPAD) ((_Float16*)hbuf)[tid] = (_Float16)0.0f;

    // 24 A fragments (96 AGPR dwords), AGPR-parked.
    LOADF(0,0) LOADF(0,1) LOADF(0,2) LOADF(0,3)
    LOADF(1,0) LOADF(1,1) LOADF(1,2) LOADF(1,3)
    LOADF(2,0) LOADF(2,1) LOADF(2,2) LOADF(2,3)
    LOADF(3,0) LOADF(3,1) LOADF(3,2) LOADF(3,3)
    LOADF(4,0) LOADF(4,1) LOADF(4,2) LOADF(4,3)
    LOADF(5,0) LOADF(5,1) LOADF(5,2) LOADF(5,3)

    const float  bhn   = b_hh[2 * HID + j];
    const float* projj = proj + j;                     // per-lane base, invariant
    float hold = 0.0f;

    // Software-pipelined token/proj lookups (1 step of slack, L2-resident).
    int tok0 = x[0];
    float xr = projj[tok0 * NPROJ];
    float xz = projj[tok0 * NPROJ + HID];
    float xn = projj[tok0 * NPROJ + 2 * HID];
    int tok_next = x[1];

    h16x8 b0, b1, b2, b3;
    __syncthreads();
    B_LOAD(0);                                         // prologue B-prep

    for (int t = 0; t < SEQN; t += 2) {
        STEP(0, 1, 0)
        STEP(1, 0, 1)
    }

    if (active) out[j] = hold;
}

extern "C" void kernel_launch(void* const* d_in, const int* in_sizes, int n_in,
                              void* d_out, int out_size, void* d_ws, size_t ws_size,
                              hipStream_t stream)
{
    const int*   x    = (const int*)  d_in[0];
    const float* emb  = (const float*)d_in[1];
    const float* w_ih = (const float*)d_in[2];
    const float* w_hh = (const float*)d_in[3];
    const float* b_ih = (const float*)d_in[4];
    const float* b_hh = (const float*)d_in[5];
    float* out = (float*)d_out;

    float*    proj  = (float*)d_ws;                        // 18000 f32 = 72 KB
    _Float16* afrag = (_Float16*)(proj + VOCAB * NPROJ);   // 49152 f16 = 96 KB

    const int total = NMFW * MT * KS * 64 * 8;             // 49152 covers both jobs
    precompute_kernel<<<(total + 255) / 256, 256, 0, stream>>>(
        emb, w_ih, b_ih, b_hh, w_hh, proj, afrag);
    gru_seq_kernel<<<1, 256, 0, stream>>>(x, b_hh, proj, afrag, out);
}

// Round 14
// 95064.380 us; speedup vs baseline: 1.7448x; 1.0700x over previous
//
#include <hip/hip_runtime.h>
#include <stdint.h>

#define VOCAB 60
#define EMB   100
#define HID   100
#define SEQN  262144
#define NPROJ 300     // 3*HID
#define HSTR  104     // h halves in LDS (100 used, 8B-aligned stride)
#define NMFW  4       // waves
#define MT    6       // M-tiles per wave (96 rows; triple-grouped)
#define KS    3       // MFMA K-steps (k<96); k in [96,100) handled by VALU tail

typedef float    f32x4 __attribute__((ext_vector_type(4)));
typedef _Float16 h16x2 __attribute__((ext_vector_type(2)));
typedef _Float16 h16x4 __attribute__((ext_vector_type(4)));
typedef _Float16 h16x8 __attribute__((ext_vector_type(8)));

__device__ __forceinline__ float fast_sig(float x) {
    return __builtin_amdgcn_rcpf(1.0f + __builtin_amdgcn_exp2f(-1.442695041f * x));
}
__device__ __forceinline__ float fast_tanh(float x) {
    return 2.0f * __builtin_amdgcn_rcpf(1.0f + __builtin_amdgcn_exp2f(-2.885390082f * x)) - 1.0f;
}

#if __has_builtin(__builtin_amdgcn_fdot2)
#define DOT2(A, B, C) __builtin_amdgcn_fdot2((A), (B), (C), false)
#else
__device__ __forceinline__ float DOT2(h16x2 a, h16x2 b, float c) {
    return fmaf((float)a.x, (float)b.x, fmaf((float)a.y, (float)b.y, c));
}
#endif

#define AS2(U)    __builtin_bit_cast(h16x2, (U))
#define SH2(V, I) __builtin_shufflevector((V), (V), (I), (I) + 1)

// Job 1: proj[v][j] = emb[v]·w_ih[j] + b_ih[j] + (j<200 ? b_hh[j] : 0)  (fp32)
// Job 2: afrag = W_hh in TRIPLE-GROUPED MFMA A-fragment order, KS=3 (k<96):
//   wave w, tile m, A-row rho=lane&15 (G=rho>>2, q=rho&3):
//     wh = m%3 (0=r,1=z,2=n), j = 32w + 8G + 2q + (m>=3), W-row = wh*100+j
//   k = ks*32 + (lane>>4)*8 + e            [j-mapping r12-verified]
// Job 3: wtail[(g*HID+j)*4+e] = w_hh[(g*HID+j)*HID + 96 + e]  (k-tail weights)
__global__ void precompute_kernel(const float* __restrict__ emb,
                                  const float* __restrict__ w_ih,
                                  const float* __restrict__ b_ih,
                                  const float* __restrict__ b_hh,
                                  const float* __restrict__ w_hh,
                                  float* __restrict__ proj,
                                  _Float16* __restrict__ afrag,
                                  _Float16* __restrict__ wtail)
{
    int idx = blockIdx.x * blockDim.x + threadIdx.x;
    if (idx < VOCAB * NPROJ) {
        int v = idx / NPROJ, j = idx - v * NPROJ;
        float acc = b_ih[j] + (j < 2 * HID ? b_hh[j] : 0.0f);
        const float* er = emb  + v * EMB;
        const float* wr = w_ih + j * EMB;
        #pragma unroll 4
        for (int k = 0; k < EMB; ++k) acc = fmaf(er[k], wr[k], acc);
        proj[idx] = acc;
    }
    if (idx < NMFW * MT * KS * 64 * 8) {      // 36864 halves
        int e    = idx & 7;
        int lane = (idx >> 3) & 63;
        int q0   = idx >> 9;
        int ks   = q0 % KS;
        int q1   = q0 / KS;
        int m    = q1 % MT;
        int w    = q1 / MT;
        int rho  = lane & 15;
        int G    = rho >> 2, q = rho & 3;
        int wh   = m % 3;
        int j    = 32 * w + 8 * G + 2 * q + (m >= 3 ? 1 : 0);
        int k    = ks * 32 + ((lane >> 4) << 3) + e;
        afrag[idx] = (j < HID)
                   ? (_Float16)w_hh[(wh * HID + j) * HID + k] : (_Float16)0.0f;
    }
    if (idx < 3 * HID * 4) {                  // 1200 halves
        int e = idx & 3;
        int row = idx >> 2;                   // g*HID + j
        wtail[idx] = (_Float16)w_hh[row * HID + 96 + e];
    }
}

#define MFMA(A, B, C) __builtin_amdgcn_mfma_f32_16x16x32_f16((A), (B), (C), 0, 0, 0)

#define LOADF(M, K) \
    h16x8 af_##M##_##K = *(const h16x8*)(afrag + ((((wave*MT+(M))*KS+(K))*64) + lane) * 8);

// v_mov pin: opaque definition -> not rematerializable (r8-proven).
#define PIN(D) asm("v_mov_b32 %0, %0" : "+v"(D));

// Cheap barrier: drain LDS only; leave global prefetch (vmcnt) in flight.
#define BAR() asm volatile("s_waitcnt lgkmcnt(0)\n\ts_barrier" ::: "memory")

// B-prep for next step: 3 broadcast b128 (k<96) + 1 broadcast b64 (k-tail).
#define B_LOAD(BUF) {                                   \
    const _Float16* hp_ = hbuf[BUF];                    \
    b0  = *(const h16x8*)(hp_ +  0 + ko);               \
    b1  = *(const h16x8*)(hp_ + 32 + ko);               \
    b2  = *(const h16x8*)(hp_ + 64 + ko);               \
    hb4 = *(const h16x4*)(hp_ + 96); }

// One GRU step. CUR/NXT compile-time buffer indices; TOFF in {0,1}.
#define STEP(CUR, NXT, TOFF) {                                              \
    /* pins: loop-carried AGPR fragments, consumed in place by MFMA */      \
    asm("" : "+a"(af_0_0), "+a"(af_0_1), "+a"(af_0_2), "+a"(af_1_0), "+a"(af_1_1)); \
    asm("" : "+a"(af_1_2), "+a"(af_2_0), "+a"(af_2_1), "+a"(af_2_2), "+a"(af_3_0)); \
    asm("" : "+a"(af_3_1), "+a"(af_3_2), "+a"(af_4_0), "+a"(af_4_1), "+a"(af_4_2)); \
    asm("" : "+a"(af_5_0), "+a"(af_5_1), "+a"(af_5_2));                     \
    /* scalar token/prefetch: SALU base + loop-invariant lane offset */     \
    int tt_ = t + (TOFF);                                                   \
    int tok_nn = x[(tt_ + 2 < SEQN) ? (tt_ + 2) : (SEQN - 1)];              \
    int tok_s  = __builtin_amdgcn_readfirstlane(tok_next);                  \
    const float* pb_ = projj + tok_s * NPROJ;                               \
    float xr_n = pb_[0];                                                    \
    float xz_n = pb_[HID];                                                  \
    float xn_n = pb_[2 * HID];                                              \
    /* 18 MFMA: 6 chains x 3 K-steps, 6-wide interleave */                  \
    f32x4 zz = {0.f, 0.f, 0.f, 0.f};                                        \
    f32x4 ac0, ac1, ac2, ac3, ac4, ac5;                                     \
    ac0 = MFMA(af_0_0, b0, zz);  ac3 = MFMA(af_3_0, b0, zz);                \
    ac1 = MFMA(af_1_0, b0, zz);  ac4 = MFMA(af_4_0, b0, zz);                \
    ac2 = MFMA(af_2_0, b0, zz);  ac5 = MFMA(af_5_0, b0, zz);                \
    ac0 = MFMA(af_0_1, b1, ac0); ac3 = MFMA(af_3_1, b1, ac3);               \
    ac1 = MFMA(af_1_1, b1, ac1); ac4 = MFMA(af_4_1, b1, ac4);               \
    ac2 = MFMA(af_2_1, b1, ac2); ac5 = MFMA(af_5_1, b1, ac5);               \
    ac0 = MFMA(af_0_2, b2, ac0); ac3 = MFMA(af_3_2, b2, ac3);               \
    ac1 = MFMA(af_1_2, b2, ac1); ac4 = MFMA(af_4_2, b2, ac4);               \
    ac2 = MFMA(af_2_2, b2, ac2); ac5 = MFMA(af_5_2, b2, ac5);               \
    /* k-tail h slices */                                                   \
    h16x2 hb01 = SH2(hb4, 0), hb23 = SH2(hb4, 2);                           \
    /* R gate early (fills MFMA pipe shadow) */                             \
    f32x4 acR = hi ? ac3 : ac0;                                             \
    float sRl = (q2 & 1) ? acR[1] : acR[0], sRh = (q2 & 1) ? acR[3] : acR[2]; \
    float sR  = (q2 & 2) ? sRh : sRl;                                       \
    float tR  = DOT2(AS2(wtR01), hb01, DOT2(AS2(wtR23), hb23, 0.0f));       \
    float r   = fast_sig(sR + tR + xr);                                     \
    /* Z gate */                                                            \
    f32x4 acZ = hi ? ac4 : ac1;                                             \
    float sZl = (q2 & 1) ? acZ[1] : acZ[0], sZh = (q2 & 1) ? acZ[3] : acZ[2]; \
    float sZ  = (q2 & 2) ? sZh : sZl;                                       \
    float tZ  = DOT2(AS2(wtZ01), hb01, DOT2(AS2(wtZ23), hb23, 0.0f));       \
    float z   = fast_sig(sZ + tZ + xz);                                     \
    /* N gate (serial tail) */                                              \
    f32x4 acN = hi ? ac5 : ac2;                                             \
    float sNl = (q2 & 1) ? acN[1] : acN[0], sNh = (q2 & 1) ? acN[3] : acN[2]; \
    float sN  = (q2 & 2) ? sNh : sNl;                                       \
    float tN  = DOT2(AS2(wtN01), hb01, DOT2(AS2(wtN23), hb23, 0.0f));       \
    float n   = fast_tanh(xn + r * (sN + tN + bhn));                        \
    float hnew = n + z * (hold - n);                                        \
    hold = hnew;                                                            \
    if (active) hbuf[NXT][j] = (_Float16)hnew;                              \
    BAR();                                                                  \
    B_LOAD(NXT);            /* pipelined B-prep for the next step */        \
    tok_next = tok_nn;                                                      \
    xr = xr_n;  xz = xz_n;  xn = xn_n; }

// 256 threads = 4 waves (1/SIMD). Per wave: 18 MFMA (KS=3) produce (r,z,n)
// u-triples in registers; VALU dot2 tail covers k in [96,100); lane c<8 of
// each 16-lane group muxes its triple, runs the gate chain, publishes h_j.
// ONE cheap barrier/step; B-prep pipelined across the iteration; unroll x2.
__global__ __launch_bounds__(256, 1) __attribute__((amdgpu_waves_per_eu(1, 1)))
void gru_seq_kernel(const int*      __restrict__ x,
                    const float*    __restrict__ b_hh,
                    const float*    __restrict__ proj,
                    const _Float16* __restrict__ afrag,
                    const _Float16* __restrict__ wtail,
                    float*          __restrict__ out)
{
    __shared__ __align__(16) _Float16 hbuf[2][HSTR];

    const int tid  = threadIdx.x;
    const int wave = tid >> 6;
    const int lane = tid & 63;
    const int G    = lane >> 4;
    const int c    = lane & 15;
    const int ko   = (lane >> 4) << 3;                 // B k-slice offset

    const int  jv     = 32 * wave + 8 * G + c;         // valid when c<8
    const bool active = (c < 8) && (jv < HID);
    const int  j      = active ? jv : 0;
    const int  q2     = (c >> 1) & 3;                  // component selector
    const bool hi     = (c & 1);                       // tile-half selector

    if (tid < 2 * HSTR) ((_Float16*)hbuf)[tid] = (_Float16)0.0f;

    // 18 A fragments (72 AGPR dwords), AGPR-parked.
    LOADF(0,0) LOADF(0,1) LOADF(0,2)
    LOADF(1,0) LOADF(1,1) LOADF(1,2)
    LOADF(2,0) LOADF(2,1) LOADF(2,2)
    LOADF(3,0) LOADF(3,1) LOADF(3,2)
    LOADF(4,0) LOADF(4,1) LOADF(4,2)
    LOADF(5,0) LOADF(5,1) LOADF(5,2)

    // k-tail weights for this lane's j: 3 gates x 4 halves = 6 pinned dwords.
    const uint32_t* wt32 = (const uint32_t*)wtail;
    uint32_t wtR01 = wt32[(0 * HID + j) * 2],     wtR23 = wt32[(0 * HID + j) * 2 + 1];
    uint32_t wtZ01 = wt32[(1 * HID + j) * 2],     wtZ23 = wt32[(1 * HID + j) * 2 + 1];
    uint32_t wtN01 = wt32[(2 * HID + j) * 2],     wtN23 = wt32[(2 * HID + j) * 2 + 1];
    PIN(wtR01) PIN(wtR23) PIN(wtZ01) PIN(wtZ23) PIN(wtN01) PIN(wtN23)

    const float  bhn   = b_hh[2 * HID + j];
    const float* projj = proj + j;                     // per-lane base, invariant
    float hold = 0.0f;

    // Software-pipelined token/proj lookups (1 step of slack, L2-resident).
    int tok0 = x[0];
    float xr = projj[tok0 * NPROJ];
    float xz = projj[tok0 * NPROJ + HID];
    float xn = projj[tok0 * NPROJ + 2 * HID];
    int tok_next = x[1];

    h16x8 b0, b1, b2;
    h16x4 hb4;
    __syncthreads();
    B_LOAD(0);                                         // prologue B-prep

    for (int t = 0; t < SEQN; t += 2) {
        STEP(0, 1, 0)
        STEP(1, 0, 1)
    }

    if (active) out[j] = hold;
}

extern "C" void kernel_launch(void* const* d_in, const int* in_sizes, int n_in,
                              void* d_out, int out_size, void* d_ws, size_t ws_size,
                              hipStream_t stream)
{
    const int*   x    = (const int*)  d_in[0];
    const float* emb  = (const float*)d_in[1];
    const float* w_ih = (const float*)d_in[2];
    const float* w_hh = (const float*)d_in[3];
    const float* b_ih = (const float*)d_in[4];
    const float* b_hh = (const float*)d_in[5];
    float* out = (float*)d_out;

    float*    proj  = (float*)d_ws;                        // 18000 f32 = 72 KB
    _Float16* afrag = (_Float16*)(proj + VOCAB * NPROJ);   // 36864 f16 = 72 KB
    _Float16* wtail = afrag + NMFW * MT * KS * 64 * 8;     // 1200 f16 = 2.4 KB

    const int total = NMFW * MT * KS * 64 * 8;             // 36864 covers all jobs
    precompute_kernel<<<(total + 255) / 256, 256, 0, stream>>>(
        emb, w_ih, b_ih, b_hh, w_hh, proj, afrag, wtail);
    gru_seq_kernel<<<1, 256, 0, stream>>>(x, b_hh, proj, afrag, wtail, out);
}

// Round 15
// 93936.780 us; speedup vs baseline: 1.7657x; 1.0120x over previous
//
#include <hip/hip_runtime.h>
#include <stdint.h>

#define VOCAB 60
#define EMB   100
#define HID   100
#define SEQN  262144
#define NPROJ 300     // 3*HID
#define HSTR  104     // h halves in LDS (100 used, 8B-aligned stride)
#define NMFW  4       // waves
#define MT    6       // M-tiles per wave (96 rows; triple-grouped)
#define KS    3       // MFMA K-steps (k<96); k in [96,100) handled by VALU tail

typedef float    f32x4 __attribute__((ext_vector_type(4)));
typedef _Float16 h16x2 __attribute__((ext_vector_type(2)));
typedef _Float16 h16x4 __attribute__((ext_vector_type(4)));
typedef _Float16 h16x8 __attribute__((ext_vector_type(8)));

__device__ __forceinline__ float fast_sig(float x) {
    return __builtin_amdgcn_rcpf(1.0f + __builtin_amdgcn_exp2f(-1.442695041f * x));
}
__device__ __forceinline__ float fast_tanh(float x) {
    return 2.0f * __builtin_amdgcn_rcpf(1.0f + __builtin_amdgcn_exp2f(-2.885390082f * x)) - 1.0f;
}

#if __has_builtin(__builtin_amdgcn_fdot2)
#define DOT2(A, B, C) __builtin_amdgcn_fdot2((A), (B), (C), false)
#else
__device__ __forceinline__ float DOT2(h16x2 a, h16x2 b, float c) {
    return fmaf((float)a.x, (float)b.x, fmaf((float)a.y, (float)b.y, c));
}
#endif

#define AS2(U)    __builtin_bit_cast(h16x2, (U))
#define SH2(V, I) __builtin_shufflevector((V), (V), (I), (I) + 1)

// Job 1: proj[v][j] = emb[v]·w_ih[j] + b_ih[j] + (j<200 ? b_hh[j] : 0)  (fp32)
// Job 2: afrag = W_hh in TRIPLE-GROUPED MFMA A-fragment order, KS=3 (k<96):
//   wave w, tile m, A-row rho=lane&15 (G=rho>>2, q=rho&3):
//     wh = m%3 (0=r,1=z,2=n), j = 32w + 8G + 2q + (m>=3), W-row = wh*100+j
//   k = ks*32 + (lane>>4)*8 + e            [r12/r14-verified]
// Job 3: wtail[(g*HID+j)*4+e] = w_hh[(g*HID+j)*HID + 96 + e]  (k-tail weights)
__global__ void precompute_kernel(const float* __restrict__ emb,
                                  const float* __restrict__ w_ih,
                                  const float* __restrict__ b_ih,
                                  const float* __restrict__ b_hh,
                                  const float* __restrict__ w_hh,
                                  float* __restrict__ proj,
                                  _Float16* __restrict__ afrag,
                                  _Float16* __restrict__ wtail)
{
    int idx = blockIdx.x * blockDim.x + threadIdx.x;
    if (idx < VOCAB * NPROJ) {
        int v = idx / NPROJ, j = idx - v * NPROJ;
        float acc = b_ih[j] + (j < 2 * HID ? b_hh[j] : 0.0f);
        const float* er = emb  + v * EMB;
        const float* wr = w_ih + j * EMB;
        #pragma unroll 4
        for (int k = 0; k < EMB; ++k) acc = fmaf(er[k], wr[k], acc);
        proj[idx] = acc;
    }
    if (idx < NMFW * MT * KS * 64 * 8) {      // 36864 halves
        int e    = idx & 7;
        int lane = (idx >> 3) & 63;
        int q0   = idx >> 9;
        int ks   = q0 % KS;
        int q1   = q0 / KS;
        int m    = q1 % MT;
        int w    = q1 / MT;
        int rho  = lane & 15;
        int G    = rho >> 2, q = rho & 3;
        int wh   = m % 3;
        int j    = 32 * w + 8 * G + 2 * q + (m >= 3 ? 1 : 0);
        int k    = ks * 32 + ((lane >> 4) << 3) + e;
        afrag[idx] = (j < HID)
                   ? (_Float16)w_hh[(wh * HID + j) * HID + k] : (_Float16)0.0f;
    }
    if (idx < 3 * HID * 4) {                  // 1200 halves
        int e = idx & 3;
        int row = idx >> 2;                   // g*HID + j
        wtail[idx] = (_Float16)w_hh[row * HID + 96 + e];
    }
}

#define MFMA(A, B, C) __builtin_amdgcn_mfma_f32_16x16x32_f16((A), (B), (C), 0, 0, 0)

#define LOADF(M, K) \
    h16x8 af_##M##_##K = *(const h16x8*)(afrag + ((((wave*MT+(M))*KS+(K))*64) + lane) * 8);

// v_mov pin: opaque definition -> not rematerializable (r8-proven).
#define PIN(D) asm("v_mov_b32 %0, %0" : "+v"(D));

// Cheap barrier: drain LDS only; leave global prefetch (vmcnt) in flight.
#define BAR() asm volatile("s_waitcnt lgkmcnt(0)\n\ts_barrier" ::: "memory")

// B-prep for next step: 3 broadcast b128 (k<96) + 1 broadcast b64 (k-tail).
#define B_LOAD(BUF) {                                   \
    const _Float16* hp_ = hbuf[BUF];                    \
    b0  = *(const h16x8*)(hp_ +  0 + ko);               \
    b1  = *(const h16x8*)(hp_ + 32 + ko);               \
    b2  = *(const h16x8*)(hp_ + 64 + ko);               \
    hb4 = *(const h16x4*)(hp_ + 96); }

// One GRU step. CUR/NXT compile-time buffer indices; TOKSRC = token of step t+1.
// Gate-ordered: R chains -> R gate -> Z chains -> Z gate -> N chains -> N tail.
#define STEP(CUR, NXT, TOKSRC) {                                            \
    /* pins: loop-carried AGPR fragments, consumed in place by MFMA */      \
    asm("" : "+a"(af_0_0), "+a"(af_0_1), "+a"(af_0_2), "+a"(af_1_0), "+a"(af_1_1)); \
    asm("" : "+a"(af_1_2), "+a"(af_2_0), "+a"(af_2_1), "+a"(af_2_2), "+a"(af_3_0)); \
    asm("" : "+a"(af_3_1), "+a"(af_3_2), "+a"(af_4_0), "+a"(af_4_1), "+a"(af_4_2)); \
    asm("" : "+a"(af_5_0), "+a"(af_5_1), "+a"(af_5_2));                     \
    /* proj prefetch for step t+1 (scalar token, SALU-scaled base) */       \
    int ts_ = __builtin_amdgcn_readfirstlane(TOKSRC);                       \
    const float* pb_ = projj + ts_ * NPROJ;                                 \
    float xr_n = pb_[0];                                                    \
    float xz_n = pb_[HID];                                                  \
    float xn_n = pb_[2 * HID];                                              \
    h16x2 hb01 = SH2(hb4, 0), hb23 = SH2(hb4, 2);                           \
    /* R chains (tiles 0,3) */                                              \
    f32x4 ac0, ac3;                                                         \
    ac0 = MFMA(af_0_0, b0, zz);  ac3 = MFMA(af_3_0, b0, zz);                \
    ac0 = MFMA(af_0_1, b1, ac0); ac3 = MFMA(af_3_1, b1, ac3);               \
    ac0 = MFMA(af_0_2, b2, ac0); ac3 = MFMA(af_3_2, b2, ac3);               \
    /* R gate (runs in the shadow of Z/N MFMAs below) */                    \
    f32x4 acR = hi ? ac3 : ac0;                                             \
    float sRl = (q2 & 1) ? acR[1] : acR[0], sRh = (q2 & 1) ? acR[3] : acR[2]; \
    float sR  = (q2 & 2) ? sRh : sRl;                                       \
    float tR  = DOT2(AS2(wtR01), hb01, DOT2(AS2(wtR23), hb23, 0.0f));       \
    float r   = fast_sig(sR + tR + xr);                                     \
    /* Z chains (tiles 1,4) */                                              \
    f32x4 ac1, ac4;                                                         \
    ac1 = MFMA(af_1_0, b0, zz);  ac4 = MFMA(af_4_0, b0, zz);                \
    ac1 = MFMA(af_1_1, b1, ac1); ac4 = MFMA(af_4_1, b1, ac4);               \
    ac1 = MFMA(af_1_2, b2, ac1); ac4 = MFMA(af_4_2, b2, ac4);               \
    f32x4 acZ = hi ? ac4 : ac1;                                             \
    float sZl = (q2 & 1) ? acZ[1] : acZ[0], sZh = (q2 & 1) ? acZ[3] : acZ[2]; \
    float sZ  = (q2 & 2) ? sZh : sZl;                                       \
    float tZ  = DOT2(AS2(wtZ01), hb01, DOT2(AS2(wtZ23), hb23, 0.0f));       \
    float z   = fast_sig(sZ + tZ + xz);                                     \
    /* N chains (tiles 2,5) */                                              \
    f32x4 ac2, ac5;                                                         \
    ac2 = MFMA(af_2_0, b0, zz);  ac5 = MFMA(af_5_0, b0, zz);                \
    ac2 = MFMA(af_2_1, b1, ac2); ac5 = MFMA(af_5_1, b1, ac5);               \
    ac2 = MFMA(af_2_2, b2, ac2); ac5 = MFMA(af_5_2, b2, ac5);               \
    f32x4 acN = hi ? ac5 : ac2;                                             \
    float sNl = (q2 & 1) ? acN[1] : acN[0], sNh = (q2 & 1) ? acN[3] : acN[2]; \
    float sN  = (q2 & 2) ? sNh : sNl;                                       \
    float tN  = DOT2(AS2(wtN01), hb01, DOT2(AS2(wtN23), hb23, 0.0f));       \
    float n   = fast_tanh(xn + r * (sN + tN + bhn));                        \
    float hnew = n + z * (hold - n);                                        \
    hold = hnew;                                                            \
    if (active) hbuf[NXT][j] = (_Float16)hnew;                              \
    BAR();                                                                  \
    B_LOAD(NXT);            /* pipelined B-prep for the next step */        \
    xr = xr_n;  xz = xz_n;  xn = xn_n; }

// 256 threads = 4 waves (1/SIMD). Per wave: 18 MFMA (KS=3, gate-ordered) give
// (r,z,n) u-triples in registers; dot2 tail covers k in [96,100); lane c<8 of
// each 16-lane group muxes its triple and runs the gate chain; R/Z gates hide
// under later MFMA chains. ONE cheap barrier/step; B-prep pipelined; unroll x4
// with a quad token queue (one aligned int4 load per 4 steps).
__global__ __launch_bounds__(256, 1) __attribute__((amdgpu_waves_per_eu(1, 1)))
void gru_seq_kernel(const int*      __restrict__ x,
                    const float*    __restrict__ b_hh,
                    const float*    __restrict__ proj,
                    const _Float16* __restrict__ afrag,
                    const _Float16* __restrict__ wtail,
                    float*          __restrict__ out)
{
    __shared__ __align__(16) _Float16 hbuf[2][HSTR];

    const int tid  = threadIdx.x;
    const int wave = tid >> 6;
    const int lane = tid & 63;
    const int G    = lane >> 4;
    const int c    = lane & 15;
    const int ko   = (lane >> 4) << 3;                 // B k-slice offset

    const int  jv     = 32 * wave + 8 * G + c;         // valid when c<8
    const bool active = (c < 8) && (jv < HID);
    const int  j      = active ? jv : 0;
    const int  q2     = (c >> 1) & 3;                  // component selector
    const bool hi     = (c & 1);                       // tile-half selector

    if (tid < 2 * HSTR) ((_Float16*)hbuf)[tid] = (_Float16)0.0f;

    // 18 A fragments (72 AGPR dwords), AGPR-parked.
    LOADF(0,0) LOADF(0,1) LOADF(0,2)
    LOADF(1,0) LOADF(1,1) LOADF(1,2)
    LOADF(2,0) LOADF(2,1) LOADF(2,2)
    LOADF(3,0) LOADF(3,1) LOADF(3,2)
    LOADF(4,0) LOADF(4,1) LOADF(4,2)
    LOADF(5,0) LOADF(5,1) LOADF(5,2)

    // k-tail weights for this lane's j: 3 gates x 4 halves = 6 pinned dwords.
    const uint32_t* wt32 = (const uint32_t*)wtail;
    uint32_t wtR01 = wt32[(0 * HID + j) * 2],     wtR23 = wt32[(0 * HID + j) * 2 + 1];
    uint32_t wtZ01 = wt32[(1 * HID + j) * 2],     wtZ23 = wt32[(1 * HID + j) * 2 + 1];
    uint32_t wtN01 = wt32[(2 * HID + j) * 2],     wtN23 = wt32[(2 * HID + j) * 2 + 1];
    PIN(wtR01) PIN(wtR23) PIN(wtZ01) PIN(wtZ23) PIN(wtN01) PIN(wtN23)

    const float  bhn   = b_hh[2 * HID + j];
    const float* projj = proj + j;                     // per-lane base, invariant
    float hold = 0.0f;

    // Token quad queue: qA = x[t..t+3], qB = x[t+4..t+7] (aligned int4 loads).
    int4 qA = *(const int4*)(x);
    int4 qB = *(const int4*)(x + 4);

    // Pipeline init: step 0 proj from token 0.
    int tok0 = __builtin_amdgcn_readfirstlane(qA.x);
    float xr = projj[tok0 * NPROJ];
    float xz = projj[tok0 * NPROJ + HID];
    float xn = projj[tok0 * NPROJ + 2 * HID];

    const f32x4 zz = {0.f, 0.f, 0.f, 0.f};
    h16x8 b0, b1, b2;
    h16x4 hb4;
    __syncthreads();
    B_LOAD(0);                                         // prologue B-prep

    for (int t = 0; t < SEQN; t += 4) {
        // Load the quad for steps t+8..t+11 (clamped near the end; uniform).
        int  ldix = (t + 8 <= SEQN - 4) ? (t + 8) : (SEQN - 4);
        int4 qC   = *(const int4*)(x + ldix);

        STEP(0, 1, qA.y)     // step t   : prefetch token t+1
        STEP(1, 0, qA.z)     // step t+1 : prefetch token t+2
        STEP(0, 1, qA.w)     // step t+2 : prefetch token t+3
        STEP(1, 0, qB.x)     // step t+3 : prefetch token t+4

        qA = qB;  qB = qC;
    }

    if (active) out[j] = hold;
}

extern "C" void kernel_launch(void* const* d_in, const int* in_sizes, int n_in,
                              void* d_out, int out_size, void* d_ws, size_t ws_size,
                              hipStream_t stream)
{
    const int*   x    = (const int*)  d_in[0];
    const float* emb  = (const float*)d_in[1];
    const float* w_ih = (const float*)d_in[2];
    const float* w_hh = (const float*)d_in[3];
    const float* b_ih = (const float*)d_in[4];
    const float* b_hh = (const float*)d_in[5];
    float* out = (float*)d_out;

    float*    proj  = (float*)d_ws;                        // 18000 f32 = 72 KB
    _Float16* afrag = (_Float16*)(proj + VOCAB * NPROJ);   // 36864 f16 = 72 KB
    _Float16* wtail = afrag + NMFW * MT * KS * 64 * 8;     // 1200 f16 = 2.4 KB

    const int total = NMFW * MT * KS * 64 * 8;             // 36864 covers all jobs
    precompute_kernel<<<(total + 255) / 256, 256, 0, stream>>>(
        emb, w_ih, b_ih, b_hh, w_hh, proj, afrag, wtail);
    gru_seq_kernel<<<1, 256, 0, stream>>>(x, b_hh, proj, afrag, wtail, out);
}